// Round 7
// baseline (540.091 us; speedup 1.0000x reference)
//
#include <hip/hip_runtime.h>

// Problem constants (from reference)
#define NUM_NODES 100000
#define MAX_DEGREE 128
#define NODE_DIM 256
#define VERT_NUM 16384
#define NUM_SAMPLES 32
#define SENTINEL (NUM_NODES - 1)

#define VPB 16                   // vertices per block
#define NBLK (VERT_NUM / VPB)    // 1024 blocks

// Output layout (FLOAT32 elements), concatenated in reference return order:
// adj_out [V*S] | att_lists [V*S] | adj_lists_numnz [V] | out_mean [V]
#define ADJ_OFF 0
#define ATT_OFF (VERT_NUM * NUM_SAMPLES)
#define NNZ_OFF (2 * VERT_NUM * NUM_SAMPLES)
#define MEAN_OFF (2 * VERT_NUM * NUM_SAMPLES + VERT_NUM)

__device__ __forceinline__ float bfbits2f(unsigned int bits16) {
    return __uint_as_float(bits16 << 16);
}

// Probe: is float storage f32 (1) or packed bf16 (0)?
// Packed bf16: each 32-bit word's LOW half is a bf16 with exponent bits
// [14:7] near 110..128 for N(0,1) data and nonzero. f32 storage: those bits
// are mid-mantissa noise (~20% in-range hits). 64 samples, cut at 40.
__device__ __forceinline__ int probe_isf32(const void* p) {
    const unsigned int* fu = (const unsigned int*)p;
    int cnt = 0;
    for (int i = 0; i < 64; ++i) {
        const unsigned int w = fu[i];
        const unsigned int e2 = (w >> 7) & 0xFFu;
        if (e2 >= 90u && e2 <= 140u && (w & 0xFFFFu) != 0u) ++cnt;
    }
    return (cnt >= 40) ? 0 : 1;
}
__device__ __forceinline__ float ldf(const void* p, size_t idx, int isf32) {
    return isf32 ? ((const float*)p)[idx]
                 : bfbits2f(((const unsigned short*)p)[idx]);
}

// ---------------------------------------------------------------------------
// Fused kernel: 16 vertices/block, LDS-staged, fp64 accumulate with f32
// materialization at each tensor boundary (l, out) to track the np ref.
// Outputs written as FLOAT32 (the harness-documented dtype for this ref).
// ---------------------------------------------------------------------------
__global__ __launch_bounds__(256)
void FastMLNeighborSampler___9337258901923_kernel(
    const int* ids,
    const int* unif_rand,
    const int* adj_info,
    const void* features_raw,
    const void* W_raw,
    const void* bias_raw,
    float* out) {
    __shared__ float A_s[VPB][NODE_DIM + 4];
    __shared__ float L_s[VPB][NODE_DIM + 4];
    __shared__ int s_ids[VPB];
    __shared__ int s_ur[NUM_SAMPLES];
    __shared__ int s_adj[VPB][NUM_SAMPLES];
    __shared__ float s_out[VPB][NUM_SAMPLES];
    __shared__ int s_isf32;

    const int tid = threadIdx.x;
    const int v0 = blockIdx.x * VPB;

    if (tid == 0) s_isf32 = probe_isf32(features_raw);
    if (tid < VPB) {
        s_ids[tid] = ids[v0 + tid];
    } else if (tid < VPB + NUM_SAMPLES) {
        s_ur[tid - VPB] = unif_rand[tid - VPB];
    }
    __syncthreads();

    const int isf32 = s_isf32;

    // stage gathered feature rows into LDS as f32
    for (int i = 0; i < 4; ++i) {
        const int idx = tid + i * 256;   // 0..1023
        const int r = idx >> 6;          // 0..15
        const int cg = (idx & 63) * 4;
        const size_t base = (size_t)s_ids[r] * NODE_DIM + cg;
        A_s[r][cg + 0] = ldf(features_raw, base + 0, isf32);
        A_s[r][cg + 1] = ldf(features_raw, base + 1, isf32);
        A_s[r][cg + 2] = ldf(features_raw, base + 2, isf32);
        A_s[r][cg + 3] = ldf(features_raw, base + 3, isf32);
    }
    // gather adj samples
    for (int i = 0; i < 2; ++i) {
        const int e = tid * 2 + i;       // 0..511
        const int r = e >> 5;
        const int s = e & 31;
        s_adj[r][s] = adj_info[(size_t)s_ids[r] * MAX_DEGREE + s_ur[s]];
    }
    __syncthreads();

    // l = A@W + b; thread = output column, fp64 accumulate
    const int col = tid;
    double acc[VPB];
    for (int g = 0; g < VPB; ++g) acc[g] = 0.0;
    for (int k = 0; k < NODE_DIM; k += 4) {
        const double w0 = (double)ldf(W_raw, (size_t)(k + 0) * NODE_DIM + col, isf32);
        const double w1 = (double)ldf(W_raw, (size_t)(k + 1) * NODE_DIM + col, isf32);
        const double w2 = (double)ldf(W_raw, (size_t)(k + 2) * NODE_DIM + col, isf32);
        const double w3 = (double)ldf(W_raw, (size_t)(k + 3) * NODE_DIM + col, isf32);
        for (int g = 0; g < VPB; ++g) {
            const float4 a = *(const float4*)&A_s[g][k];
            acc[g] = fma((double)a.x, w0, acc[g]);
            acc[g] = fma((double)a.y, w1, acc[g]);
            acc[g] = fma((double)a.z, w2, acc[g]);
            acc[g] = fma((double)a.w, w3, acc[g]);
        }
    }
    {
        const double bv = (double)ldf(bias_raw, col, isf32);
        for (int g = 0; g < VPB; ++g) L_s[g][col] = (float)(acc[g] + bv);
    }
    __syncthreads();

    // per-thread full 256-dim dots: thread t does dots t and t+256
    for (int dd = 0; dd < 2; ++dd) {
        const int d = tid + dd * 256;    // 0..511
        const int g = d >> 5;
        const int s = d & 31;
        const size_t frb = (size_t)s_adj[g][s] * NODE_DIM;
        double a2 = 0.0;
        for (int c = 0; c < NODE_DIM; c += 4) {
            const float4 l = *(const float4*)&L_s[g][c];
            a2 = fma((double)ldf(features_raw, frb + c + 0, isf32), (double)l.x, a2);
            a2 = fma((double)ldf(features_raw, frb + c + 1, isf32), (double)l.y, a2);
            a2 = fma((double)ldf(features_raw, frb + c + 2, isf32), (double)l.z, a2);
            a2 = fma((double)ldf(features_raw, frb + c + 3, isf32), (double)l.w, a2);
        }
        s_out[g][s] = (float)a2;   // f32 materialization matches np einsum
    }
    __syncthreads();

    // epilogue: one thread per vertex, FLOAT32 stores
    if (tid < VPB) {
        const int g = tid;
        const int v = v0 + g;
        double sum = 0.0;
        for (int s = 0; s < NUM_SAMPLES; ++s)
            sum += (double)fmaxf(s_out[g][s], 0.0f);
        const float mean = (float)(sum * (1.0 / 32.0));
        int nnz = 0;
        for (int s = 0; s < NUM_SAMPLES; ++s) {
            const float o = fmaxf(s_out[g][s], 0.0f);
            const int nb = s_adj[g][s];
            const bool cond = (nb == SENTINEL) || (o > 0.5f * mean);
            if (!cond) ++nnz;
            out[ADJ_OFF + (size_t)v * NUM_SAMPLES + s] =
                cond ? (float)SENTINEL : (float)nb;
            out[ATT_OFF + (size_t)v * NUM_SAMPLES + s] = 1.0f;
        }
        out[NNZ_OFF + v] = (float)nnz;
        out[MEAN_OFF + v] = mean;
    }
}

extern "C" void kernel_launch(void* const* d_in, const int* in_sizes, int n_in,
                              void* d_out, int out_size, void* d_ws, size_t ws_size,
                              hipStream_t stream) {
    // Identify inputs by element count (all six distinct); fall back to
    // setup_inputs() dict order.
    const int* ids = nullptr;
    const int* unif_rand = nullptr;
    const int* adj_info = nullptr;
    const void* features = nullptr;
    const void* W = nullptr;
    const void* bias = nullptr;
    for (int i = 0; i < n_in; ++i) {
        switch (in_sizes[i]) {
            case VERT_NUM:               ids       = (const int*)d_in[i]; break;
            case NUM_SAMPLES:            unif_rand = (const int*)d_in[i]; break;
            case NUM_NODES * MAX_DEGREE: adj_info  = (const int*)d_in[i]; break;
            case NUM_NODES * NODE_DIM:   features  = (const void*)d_in[i]; break;
            case NODE_DIM * NODE_DIM:    W         = (const void*)d_in[i]; break;
            case NODE_DIM:               bias      = (const void*)d_in[i]; break;
            default: break;
        }
    }
    if (!ids || !unif_rand || !adj_info || !features || !W || !bias) {
        ids       = (const int*)d_in[0];
        unif_rand = (const int*)d_in[1];
        adj_info  = (const int*)d_in[2];
        features  = (const void*)d_in[3];
        W         = (const void*)d_in[4];
        bias      = (const void*)d_in[5];
    }
    float* out = (float*)d_out;

    FastMLNeighborSampler___9337258901923_kernel<<<NBLK, 256, 0, stream>>>(
        ids, unif_rand, adj_info, features, W, bias, out);
}